// Round 23
// baseline (274.796 us; speedup 1.0000x reference)
//
#include <hip/hip_runtime.h>
#include <hip/hip_bf16.h>

typedef __attribute__((ext_vector_type(8))) short short8;
typedef __attribute__((ext_vector_type(4))) short s4_t;
typedef __attribute__((ext_vector_type(4))) float f32x4;
typedef __attribute__((ext_vector_type(16))) float f32x16;
typedef __attribute__((ext_vector_type(2))) unsigned uint2v;
typedef __hip_bfloat16 bf16;

#define NB 2
#define NT 2048
#define NDIM 2048
#define NH 16
#define NHD 128
#define NDC 512
#define NDR 64

// async global->LDS, 16B per lane; lds base must be wave-uniform (HW: base + lane*16)
__device__ __forceinline__ void gl_lds16(const bf16* g, bf16* l){
  __builtin_amdgcn_global_load_lds(
      (const __attribute__((address_space(1))) void*)(const void*)g,
      (__attribute__((address_space(3))) void*)(void*)l, 16, 0, 0);
}

static __device__ inline unsigned cvtpk(float lo, float hi){
  unsigned u;
  asm("v_cvt_pk_bf16_f32 %0, %1, %2" : "=v"(u) : "v"(lo), "v"(hi));
  return u;
}

// ---------------- f32 -> bf16 convert (x) ----------------
__global__ __launch_bounds__(256) void cvt_kernel(const float* __restrict__ src, bf16* __restrict__ dst){
  int i = (blockIdx.x*256 + threadIdx.x)*4;
  float4 v = *(const float4*)(src + i);
  dst[i+0] = __float2bfloat16(v.x);
  dst[i+1] = __float2bfloat16(v.y);
  dst[i+2] = __float2bfloat16(v.z);
  dst[i+3] = __float2bfloat16(v.w);
}

// ---------------- batched transpose+convert: 8 weights in one launch ----------------
struct TAll {
  const float* src[8];
  bf16* dst[8];
  int K[8];
  int N[8];
  int cum[9];
};
__global__ __launch_bounds__(256) void tconv_all(TAll a){
  __shared__ float tile[32][33];
  int bid = blockIdx.x;
  int i = 0;
  #pragma unroll
  for (int j=0;j<8;j++) if (bid >= a.cum[j+1]) i = j+1;
  const float* W = a.src[i];
  bf16* Wt = a.dst[i];
  int K = a.K[i], N = a.N[i];
  int tl = bid - a.cum[i];
  int ntx = N >> 5;
  int n0 = (tl % ntx)*32, k0 = (tl / ntx)*32;
  int tx = threadIdx.x & 31, ty = threadIdx.x >> 5;
  #pragma unroll
  for (int j=0;j<32;j+=8) tile[ty+j][tx] = W[(size_t)(k0+ty+j)*N + n0 + tx];
  __syncthreads();
  #pragma unroll
  for (int j=0;j<32;j+=8) Wt[(size_t)(n0+ty+j)*K + k0 + tx] = __float2bfloat16(tile[tx][ty+j]);
}

// ---------------- GEMM: C[M,N] = A[M,K] @ Bt[N,K]^T  (bf16 in, f32 acc) ----------------
// m97 structure: global_load_lds width-16 staging into linear LDS, 2 barriers/K-step.
// MODE 0: C bf16 row-major [M,N] (guarded on N)
// MODE 2: Cf f32 row-major [M,N] + bias
// MODE 4: KV merged: gc<2048 -> Kf heads layout (C); else -> V^T layout [bh][d][t] (C2)
// MODE 5: QQR merged: gc<2048 -> Qf heads layout *mult (C); else -> fused Q-RoPE into
//         Qf[...,128+2i] (rotation pair (i,i+32) lives in nj and nj^2 of same thread)
template<int MODE>
__global__ __launch_bounds__(256,3) void gemm_bt(const bf16* __restrict__ A,
    const bf16* __restrict__ Bt, bf16* __restrict__ C, bf16* __restrict__ C2,
    float* __restrict__ Cf, const float* __restrict__ bias,
    int M, int N, int K, int lda, float mult)
{
  __shared__ bf16 As[128*64];
  __shared__ bf16 Bs[128*64];
  const int m0 = blockIdx.x*128, n0 = blockIdx.y*128;
  const int t = threadIdx.x, lane = t&63, w = t>>6;
  const int wr = w>>1, wc = w&1;
  const int l15 = lane&15, lg = lane>>4;
  const int wbase = t & 192;   // w*64

  f32x4 acc[4][4];
  #pragma unroll
  for (int mi=0;mi<4;mi++)
    #pragma unroll
    for (int nj=0;nj<4;nj++) acc[mi][nj] = (f32x4){0.f,0.f,0.f,0.f};

  for (int k0=0;k0<K;k0+=64){
    __syncthreads();
    #pragma unroll
    for (int j=0;j<4;j++){
      int c = j*256 + t;
      int r = c>>3, cc = (c&7)*8;
      gl_lds16(A + (size_t)(m0+r)*lda + k0 + cc, As + (size_t)(j*256 + wbase)*8);
      int bn = n0 + r; if (bn > N-1) bn = N-1;
      gl_lds16(Bt + (size_t)bn*K + k0 + cc, Bs + (size_t)(j*256 + wbase)*8);
    }
    __syncthreads();
    #pragma unroll
    for (int kk=0;kk<2;kk++){
      short8 af[4], bfv[4];
      #pragma unroll
      for (int mi=0;mi<4;mi++) af[mi] = *(const short8*)&As[(wr*64+mi*16+l15)*64 + kk*32+lg*8];
      #pragma unroll
      for (int nj=0;nj<4;nj++) bfv[nj] = *(const short8*)&Bs[(wc*64+nj*16+l15)*64 + kk*32+lg*8];
      #pragma unroll
      for (int mi=0;mi<4;mi++)
        #pragma unroll
        for (int nj=0;nj<4;nj++)
          acc[mi][nj] = __builtin_amdgcn_mfma_f32_16x16x32_bf16(af[mi], bfv[nj], acc[mi][nj], 0,0,0);
    }
  }

  // epilogue: D layout col=lane&15, row=(lane>>4)*4+reg  [verified m89]
  if constexpr (MODE==5){
    if (n0 >= 2048){
      // fused Q-RoPE: this block's cols are entirely q_R (boundary 2048 is block-aligned)
      int qh = (n0 - 2048 + wc*64) >> 6;
      int bidx = m0 >> 11;
      size_t hb = ((size_t)bidx*NH + qh)*(size_t)NT;
      float invf[2];
      invf[0] = __expf(-(float)l15 * 0.2878231366242557f);         // i = l15
      invf[1] = __expf(-(float)(16 + l15) * 0.2878231366242557f);  // i = 16+l15
      #pragma unroll
      for (int mi=0;mi<4;mi++){
        #pragma unroll
        for (int r2=0;r2<4;r2++){
          int tp = (m0 & 2047) + wr*64 + mi*16 + lg*4 + r2;
          #pragma unroll
          for (int bb2=0;bb2<2;bb2++){
            float x1 = acc[mi][bb2][r2];
            float x2 = acc[mi][bb2+2][r2];
            float fr = (float)tp * invf[bb2];
            float sn, cs;
            sincosf(fr, &sn, &cs);
            float o0 = (x1*cs - x2*sn)*mult;
            float o1 = (x1*sn + x2*cs)*mult;
            int i2 = (bb2<<4) + l15;
            *(unsigned*)&C[(hb + tp)*192 + 128 + 2*i2] = cvtpk(o0, o1);
          }
        }
      }
      return;
    }
  }
  #pragma unroll
  for (int mi=0;mi<4;mi++){
    #pragma unroll
    for (int nj=0;nj<4;nj++){
      f32x4 v = acc[mi][nj];
      int gr0 = m0 + wr*64 + mi*16 + lg*4;
      int gc  = n0 + wc*64 + nj*16 + l15;
      if constexpr (MODE==0){
        if (gc < N){
          #pragma unroll
          for (int r2=0;r2<4;r2++) C[(size_t)(gr0+r2)*N + gc] = __float2bfloat16(v[r2]*mult);
        }
      } else if constexpr (MODE==2){
        float bb = bias[gc];
        #pragma unroll
        for (int r2=0;r2<4;r2++) Cf[(size_t)(gr0+r2)*N + gc] = v[r2]*mult + bb;
      } else if constexpr (MODE==4){
        int bidx = m0 >> 11;
        int tl0 = (m0 & 2047) + wr*64 + mi*16 + lg*4;
        if (gc < 2048){
          int hq = gc >> 7, dl = gc & 127;
          size_t base = ((size_t)bidx*NH + hq)*(size_t)NT;
          #pragma unroll
          for (int r2=0;r2<4;r2++) C[(base + tl0 + r2)*192 + dl] = __float2bfloat16(v[r2]);
        } else {
          int g2 = gc - 2048;
          int hq = g2 >> 7, dl = g2 & 127;
          s4_t pk;
          #pragma unroll
          for (int r2=0;r2<4;r2++){
            union { bf16 b; unsigned short u; } cvu;
            cvu.b = __float2bfloat16(v[r2]);
            pk[r2] = (short)cvu.u;
          }
          *(s4_t*)&C2[(((size_t)bidx*NH + hq)*NHD + dl)*NT + tl0] = pk;
        }
      } else { // MODE 5, Q half (n0 < 2048)
        int bidx = m0 >> 11;
        int tl0 = (m0 & 2047) + wr*64 + mi*16 + lg*4;
        int hq = gc >> 7, dl = gc & 127;
        size_t base = ((size_t)bidx*NH + hq)*(size_t)NT;
        #pragma unroll
        for (int r2=0;r2<4;r2++) C[(base + tl0 + r2)*192 + dl] = __float2bfloat16(v[r2]*mult);
      }
    }
  }
}

// ---------------- K-RoPE (krp in combined buffer, row stride 1088) ----------------
__global__ __launch_bounds__(128) void rope_k(const bf16* __restrict__ krp,
    bf16* __restrict__ Kf)
{
  int bt = blockIdx.x*2 + (threadIdx.x>>6);
  int d = threadIdx.x & 63;
  int b = bt >> 11, tpos = bt & 2047;
  int i = d >> 1;
  float inv = __expf(-(float)i * 0.2878231366242557f);
  float fr = (float)tpos * inv;
  float sn, cs;
  sincosf(fr, &sn, &cs);

  float x1 = __bfloat162float(krp[(size_t)bt*1088 + i]);
  float x2 = __bfloat162float(krp[(size_t)bt*1088 + 32 + i]);
  float kv = (d&1) ? (x1*sn + x2*cs) : (x1*cs - x2*sn);
  bf16 kvb = __float2bfloat16(kv);
  size_t base = ((size_t)b*NH*NT + tpos)*192;
  #pragma unroll
  for (int h=0;h<NH;h++) Kf[base + (size_t)h*NT*192 + 128 + d] = kvb;
}

// ---------------- Flash attention (swapped-operand, 32x32x16) ----------------
// 8-wave block, QBLK=256, DMA staging (pre-swizzled source), K/V double-buffered.
// Q pre-scaled by (1/sqrt(192))*log2(e): softmax uses raw exp2f (lowered to
// v_exp_f32, which is base-2 natively). Defer-max threshold 8*log2e.
static __device__ inline void plswap(unsigned &a, unsigned &b){
  uint2v r = __builtin_amdgcn_permlane32_swap(a, b, false, false);
  a = r[0]; b = r[1];
}

__global__ __launch_bounds__(512,2) void attn_kernel(const bf16* __restrict__ Qf,
    const bf16* __restrict__ Kf, const bf16* __restrict__ Vt, bf16* __restrict__ ctx)
{
  __shared__ __align__(16) bf16 smem[40960];   // 81920 B: 2 x (12288 K + 8192 V) elems

  const int lin = blockIdx.x;
  const int swz = (lin & 7)*32 + (lin >> 3);      // 256 = 8*32 -> bijective
  const int qt = swz & 7, bh = swz >> 3;
  const int b = bh >> 4, h = bh & 15;
  const int q0 = qt * 256;
  const int t = threadIdx.x, lane = t&63, w = t>>6;   // w in 0..7
  const int l31 = lane&31, hi = lane>>5;
  const int rsw = (l31&7)<<4;
  const int hib = hi*16;
  const int wbase = t & 448;                       // wave-uniform thread base

  const bf16* Qp  = Qf + ((size_t)bh*NT + q0)*192;
  const bf16* Kp  = Kf + (size_t)bh*NT*192;
  const bf16* Vtp = Vt + (size_t)bh*NHD*NT;

  short8 qf[12];
  #pragma unroll
  for (int kk=0;kk<12;kk++)
    qf[kk] = *(const short8*)(Qp + (size_t)(w*32 + l31)*192 + kk*16 + hi*8);

  f32x16 o[4];
  #pragma unroll
  for (int Dt=0;Dt<4;Dt++)
    #pragma unroll
    for (int r=0;r<16;r++) o[Dt][r] = 0.f;
  float mrun = -1e30f, lrun = 0.f;

  // DMA-stage tile kt into buf: K 64x192 + V^T 128x64 (elems), pre-swizzled source
  auto stage = [&](int kt, bf16* buf){
    const bf16* Ksrc = Kp + (size_t)kt*64*192;
    #pragma unroll
    for (int j=0;j<3;j++){
      int c = j*512 + t;                     // 1536 chunks of 8 elems
      int r = c/24, ce = (c%24)*8;           // row, col-elem (linear dest)
      gl_lds16(Ksrc + (size_t)r*192 + (ce ^ ((r&7)<<3)), buf + (size_t)(j*512 + wbase)*8);
    }
    bf16* vb = buf + 12288;
    #pragma unroll
    for (int j=0;j<2;j++){
      int c = j*512 + t;                     // 1024 chunks
      int r = c>>3, ce = (c&7)*8;
      gl_lds16(Vtp + (size_t)r*NT + kt*64 + (ce ^ ((r&7)<<3)), vb + (size_t)(j*512 + wbase)*8);
    }
  };

  stage(0, smem);
  __syncthreads();   // drains vmcnt -> tile 0 resident

  for (int kt=0; kt<NT/64; kt++){
    const char* KsB  = (const char*)(smem + (kt&1)*20480);
    const char* VTsB = KsB + 24576;
    if (kt+1 < NT/64) stage(kt+1, smem + ((kt+1)&1)*20480);  // DMA overlaps compute

    // S^T[key][q]: A = K rows (key = Mt*32 + l31), B = Q  (S in log2e units)
    f32x16 sa[2];
    #pragma unroll
    for (int Mt=0;Mt<2;Mt++)
      #pragma unroll
      for (int r=0;r<16;r++) sa[Mt][r] = 0.f;
    __builtin_amdgcn_s_setprio(1);
    #pragma unroll
    for (int kk=0;kk<12;kk++){
      int cb = kk*32 + hib;
      short8 kf0 = *(const short8*)(KsB + (size_t)l31*384        + ((cb) ^ rsw));
      short8 kf1 = *(const short8*)(KsB + (size_t)(l31+32)*384   + ((cb) ^ rsw));
      sa[0] = __builtin_amdgcn_mfma_f32_32x32x16_bf16(kf0, qf[kk], sa[0], 0,0,0);
      sa[1] = __builtin_amdgcn_mfma_f32_32x32x16_bf16(kf1, qf[kk], sa[1], 0,0,0);
    }
    __builtin_amdgcn_s_setprio(0);

    float mx[8];
    #pragma unroll
    for (int i2=0;i2<8;i2++)
      mx[i2] = fmaxf(fmaxf(sa[0][2*i2], sa[0][2*i2+1]), fmaxf(sa[1][2*i2], sa[1][2*i2+1]));
    float tm = fmaxf(fmaxf(fmaxf(mx[0],mx[1]),fmaxf(mx[2],mx[3])),
                     fmaxf(fmaxf(mx[4],mx[5]),fmaxf(mx[6],mx[7])));
    tm = fmaxf(tm, __shfl_xor(tm, 32));

    if (__any(tm > mrun + 11.5416f)){   // 8 * log2(e)
      float mn = fmaxf(mrun, tm);
      float alpha = exp2f(mrun - mn);
      mrun = mn;
      lrun *= alpha;
      #pragma unroll
      for (int Dt=0;Dt<4;Dt++)
        #pragma unroll
        for (int r=0;r<16;r++) o[Dt][r] *= alpha;
    }

    #pragma unroll
    for (int Mt=0;Mt<2;Mt++)
      #pragma unroll
      for (int r=0;r<16;r++) sa[Mt][r] = exp2f(sa[Mt][r] - mrun);
    float sm[8];
    #pragma unroll
    for (int i2=0;i2<8;i2++)
      sm[i2] = (sa[0][2*i2] + sa[0][2*i2+1]) + (sa[1][2*i2] + sa[1][2*i2+1]);
    float rs = ((sm[0]+sm[1])+(sm[2]+sm[3])) + ((sm[4]+sm[5])+(sm[6]+sm[7]));
    rs += __shfl_xor(rs, 32);
    lrun += rs;

    short8 pf[4];
    #pragma unroll
    for (int Mt=0;Mt<2;Mt++){
      unsigned u[8];
      #pragma unroll
      for (int p8=0;p8<8;p8++) u[p8] = cvtpk(sa[Mt][2*p8], sa[Mt][2*p8+1]);
      plswap(u[0], u[2]); plswap(u[1], u[3]);
      plswap(u[4], u[6]); plswap(u[5], u[7]);
      union { unsigned du[4]; short8 s8; } f0, f1;
      f0.du[0]=u[0]; f0.du[1]=u[1]; f0.du[2]=u[2]; f0.du[3]=u[3];
      f1.du[0]=u[4]; f1.du[1]=u[5]; f1.du[2]=u[6]; f1.du[3]=u[7];
      pf[2*Mt+0] = f0.s8;
      pf[2*Mt+1] = f1.s8;
    }

    // O^T += V^T @ P^T
    __builtin_amdgcn_s_setprio(1);
    #pragma unroll
    for (int kw=0;kw<4;kw++){
      int cb = kw*32 + hib;
      #pragma unroll
      for (int Dt=0;Dt<4;Dt++){
        short8 vf = *(const short8*)(VTsB + (size_t)(Dt*32 + l31)*128 + ((cb) ^ rsw));
        o[Dt] = __builtin_amdgcn_mfma_f32_32x32x16_bf16(vf, pf[kw], o[Dt], 0,0,0);
      }
    }
    __builtin_amdgcn_s_setprio(0);
    __syncthreads();   // drains DMA for tile kt+1; protects buf reuse
  }

  float il = 1.0f / lrun;
  bf16* Es = smem;    // 256 rows x 140 elems = 71680 B < 81920 B
  const int EROW = 140;
  const int ebase = w*32*EROW;
  #pragma unroll
  for (int Dt=0;Dt<4;Dt++)
    #pragma unroll
    for (int r=0;r<16;r+=2){
      int d = Dt*32 + (r&3) + 8*(r>>2) + 4*hi;
      *(unsigned*)&Es[ebase + l31*EROW + d] = cvtpk(o[Dt][r]*il, o[Dt][r+1]*il);
    }
  __syncthreads();
  int q = lane>>1, halfd = lane&1;
  size_t gq = q0 + w*32 + q;
  size_t obase = (((size_t)b*NT + gq)*NH + h)*NHD + halfd*64;
  const int eb2 = ebase + q*EROW + halfd*64;
  #pragma unroll
  for (int pp=0;pp<8;pp++){
    union { s4_t h[2]; short8 s; } uu;
    uu.h[0] = *(const s4_t*)&Es[eb2 + pp*8];
    uu.h[1] = *(const s4_t*)&Es[eb2 + pp*8 + 4];
    *(short8*)&ctx[obase + pp*8] = uu.s;
  }
}

// ---------------- host ----------------
extern "C" void kernel_launch(void* const* d_in, const int* in_sizes, int n_in,
                              void* d_out, int out_size, void* d_ws, size_t ws_size,
                              hipStream_t stream)
{
  const float* x     = (const float*)d_in[0];
  const float* W_DKV = (const float*)d_in[1];
  const float* W_DQ  = (const float*)d_in[2];
  const float* W_UK  = (const float*)d_in[3];
  const float* W_UV  = (const float*)d_in[4];
  const float* W_UQ  = (const float*)d_in[5];
  const float* W_KR  = (const float*)d_in[6];
  const float* W_QR  = (const float*)d_in[7];
  const float* W_O   = (const float*)d_in[8];
  const float* b_O   = (const float*)d_in[9];

  // (1/sqrt(192)) * log2(e): QK^T lands in log2e units -> softmax uses raw exp2
  const float scale = 0.07216878364870323f * 1.4426950408889634f;

  char* ws = (char*)d_ws;
  bf16* xb    = (bf16*)(ws + 0);           // [4096][2048]
  bf16* wcomb = (bf16*)(ws + 16777216);    // [1088][2048]  (W_DKV^T ; W_DQ^T ; W_KR^T)
  bf16* wuk   = (bf16*)(ws + 21233664);    // [2048][512]   (contiguous with wuv)
  bf16* wuv   = (bf16*)(ws + 23330816);
  bf16* wuq   = (bf16*)(ws + 25427968);    // (contiguous with wqr)
  bf16* wqr   = (bf16*)(ws + 27525120);    // [1024][512]
  bf16* wo    = (bf16*)(ws + 28573696);    // [2048][2048]
  bf16* comb  = (bf16*)(ws + 36962304);    // [4096][1088]  (ckv | cq | krp)
  bf16* Qf    = (bf16*)(ws + 54263808);    // [2,16,2048,192]
  bf16* Kf    = (bf16*)(ws + 79429632);    // [2,16,2048,192]
  bf16* vt    = (bf16*)(ws + 104595456);   // [2,16,128,2048]  (V transposed)
  bf16* ctxb  = (bf16*)(ws + 121372672);   // [4096][2048]

  bf16* ckv = comb;          // cols 0-511,   lda 1088
  bf16* cq  = comb + 512;    // cols 512-1023
  bf16* krp = comb + 1024;   // cols 1024-1087

  cvt_kernel<<<8192,256,0,stream>>>(x, xb);

  TAll ta;
  ta.src[0]=W_DKV; ta.dst[0]=wcomb;             ta.K[0]=2048; ta.N[0]=512;
  ta.src[1]=W_DQ;  ta.dst[1]=wcomb + 512*2048;  ta.K[1]=2048; ta.N[1]=512;
  ta.src[2]=W_KR;  ta.dst[2]=wcomb + 1024*2048; ta.K[2]=2048; ta.N[2]=64;
  ta.src[3]=W_UK;  ta.dst[3]=wuk;               ta.K[3]=512;  ta.N[3]=2048;
  ta.src[4]=W_UV;  ta.dst[4]=wuv;               ta.K[4]=512;  ta.N[4]=2048;
  ta.src[5]=W_UQ;  ta.dst[5]=wuq;               ta.K[5]=512;  ta.N[5]=2048;
  ta.src[6]=W_QR;  ta.dst[6]=wqr;               ta.K[6]=512;  ta.N[6]=1024;
  ta.src[7]=W_O;   ta.dst[7]=wo;                ta.K[7]=2048; ta.N[7]=2048;
  ta.cum[0]=0;
  for (int i=0;i<8;i++) ta.cum[i+1] = ta.cum[i] + (ta.N[i]/32)*(ta.K[i]/32);
  tconv_all<<<ta.cum[8],256,0,stream>>>(ta);

  // merged x-projection: [4096,2048] @ [1088,2048]^T -> comb
  gemm_bt<0><<<dim3(32,9), 256,0,stream>>>(xb, wcomb, comb, nullptr, nullptr, nullptr, 4096, 1088, 2048, 2048, 1.0f);

  // K-RoPE (krp ready after x-proj)
  rope_k<<<2048,128,0,stream>>>(krp, Kf);

  // merged KV up-projection: ckv @ [wuk;wuv]^T  (N=4096)
  gemm_bt<4><<<dim3(32,32),256,0,stream>>>(ckv, wuk, Kf, vt, nullptr, nullptr, 4096, 4096, 512, 1088, 1.0f);
  // merged Q/QR up-projection with fused Q-RoPE: cq @ [wuq;wqr]^T  (N=3072)
  gemm_bt<5><<<dim3(32,24),256,0,stream>>>(cq, wuq, Qf, nullptr, nullptr, nullptr, 4096, 3072, 512, 1088, scale);

  attn_kernel<<<256,512,0,stream>>>(Qf, Kf, vt, ctxb);
  gemm_bt<2><<<dim3(32,16),256,0,stream>>>(ctxb, wo, nullptr, nullptr, (float*)d_out, b_O, 4096, 2048, 2048, 2048, 1.0f);
}

// Round 24
// 264.277 us; speedup vs baseline: 1.0398x; 1.0398x over previous
//
#include <hip/hip_runtime.h>
#include <hip/hip_bf16.h>

typedef __attribute__((ext_vector_type(8))) short short8;
typedef __attribute__((ext_vector_type(4))) short s4_t;
typedef __attribute__((ext_vector_type(4))) float f32x4;
typedef __attribute__((ext_vector_type(16))) float f32x16;
typedef __attribute__((ext_vector_type(2))) unsigned uint2v;
typedef __hip_bfloat16 bf16;

#define NB 2
#define NT 2048
#define NDIM 2048
#define NH 16
#define NHD 128
#define NDC 512
#define NDR 64

// async global->LDS, 16B per lane; lds base must be wave-uniform (HW: base + lane*16)
__device__ __forceinline__ void gl_lds16(const bf16* g, bf16* l){
  __builtin_amdgcn_global_load_lds(
      (const __attribute__((address_space(1))) void*)(const void*)g,
      (__attribute__((address_space(3))) void*)(void*)l, 16, 0, 0);
}

static __device__ inline unsigned cvtpk(float lo, float hi){
  unsigned u;
  asm("v_cvt_pk_bf16_f32 %0, %1, %2" : "=v"(u) : "v"(lo), "v"(hi));
  return u;
}

// ---------------- f32 -> bf16 convert (x) ----------------
__global__ __launch_bounds__(256) void cvt_kernel(const float* __restrict__ src, bf16* __restrict__ dst){
  int i = (blockIdx.x*256 + threadIdx.x)*4;
  float4 v = *(const float4*)(src + i);
  dst[i+0] = __float2bfloat16(v.x);
  dst[i+1] = __float2bfloat16(v.y);
  dst[i+2] = __float2bfloat16(v.z);
  dst[i+3] = __float2bfloat16(v.w);
}

// ---------------- batched transpose+convert: 8 weights in one launch ----------------
struct TAll {
  const float* src[8];
  bf16* dst[8];
  int K[8];
  int N[8];
  int cum[9];
};
__global__ __launch_bounds__(256) void tconv_all(TAll a){
  __shared__ float tile[32][33];
  int bid = blockIdx.x;
  int i = 0;
  #pragma unroll
  for (int j=0;j<8;j++) if (bid >= a.cum[j+1]) i = j+1;
  const float* W = a.src[i];
  bf16* Wt = a.dst[i];
  int K = a.K[i], N = a.N[i];
  int tl = bid - a.cum[i];
  int ntx = N >> 5;
  int n0 = (tl % ntx)*32, k0 = (tl / ntx)*32;
  int tx = threadIdx.x & 31, ty = threadIdx.x >> 5;
  #pragma unroll
  for (int j=0;j<32;j+=8) tile[ty+j][tx] = W[(size_t)(k0+ty+j)*N + n0 + tx];
  __syncthreads();
  #pragma unroll
  for (int j=0;j<32;j+=8) Wt[(size_t)(n0+ty+j)*K + k0 + tx] = __float2bfloat16(tile[tx][ty+j]);
}

// ---------------- GEMM: C[M,N] = A[M,K] @ Bt[N,K]^T  (bf16 in, f32 acc) ----------------
// m97 structure: global_load_lds width-16 staging into linear LDS, 2 barriers/K-step.
// MODE 0: C bf16 row-major [M,N] (guarded on N)
// MODE 2: Cf f32 row-major [M,N] + bias
// MODE 4: KV merged: gc<2048 -> Kf heads layout (C); else -> V^T layout [bh][d][t] (C2)
// MODE 5: QQR merged: gc<2048 -> Qf heads layout *mult (C); else -> fused Q-RoPE into
//         Qf[...,128+2i] (rotation pair (i,i+32) lives in nj and nj^2 of same thread)
template<int MODE>
__global__ __launch_bounds__(256,3) void gemm_bt(const bf16* __restrict__ A,
    const bf16* __restrict__ Bt, bf16* __restrict__ C, bf16* __restrict__ C2,
    float* __restrict__ Cf, const float* __restrict__ bias,
    int M, int N, int K, int lda, float mult)
{
  __shared__ bf16 As[128*64];
  __shared__ bf16 Bs[128*64];
  const int m0 = blockIdx.x*128, n0 = blockIdx.y*128;
  const int t = threadIdx.x, lane = t&63, w = t>>6;
  const int wr = w>>1, wc = w&1;
  const int l15 = lane&15, lg = lane>>4;
  const int wbase = t & 192;   // w*64

  f32x4 acc[4][4];
  #pragma unroll
  for (int mi=0;mi<4;mi++)
    #pragma unroll
    for (int nj=0;nj<4;nj++) acc[mi][nj] = (f32x4){0.f,0.f,0.f,0.f};

  for (int k0=0;k0<K;k0+=64){
    __syncthreads();
    #pragma unroll
    for (int j=0;j<4;j++){
      int c = j*256 + t;
      int r = c>>3, cc = (c&7)*8;
      gl_lds16(A + (size_t)(m0+r)*lda + k0 + cc, As + (size_t)(j*256 + wbase)*8);
      int bn = n0 + r; if (bn > N-1) bn = N-1;
      gl_lds16(Bt + (size_t)bn*K + k0 + cc, Bs + (size_t)(j*256 + wbase)*8);
    }
    __syncthreads();
    #pragma unroll
    for (int kk=0;kk<2;kk++){
      short8 af[4], bfv[4];
      #pragma unroll
      for (int mi=0;mi<4;mi++) af[mi] = *(const short8*)&As[(wr*64+mi*16+l15)*64 + kk*32+lg*8];
      #pragma unroll
      for (int nj=0;nj<4;nj++) bfv[nj] = *(const short8*)&Bs[(wc*64+nj*16+l15)*64 + kk*32+lg*8];
      #pragma unroll
      for (int mi=0;mi<4;mi++)
        #pragma unroll
        for (int nj=0;nj<4;nj++)
          acc[mi][nj] = __builtin_amdgcn_mfma_f32_16x16x32_bf16(af[mi], bfv[nj], acc[mi][nj], 0,0,0);
    }
  }

  // epilogue: D layout col=lane&15, row=(lane>>4)*4+reg  [verified m89]
  if constexpr (MODE==5){
    if (n0 >= 2048){
      // fused Q-RoPE: this block's cols are entirely q_R (boundary 2048 is block-aligned)
      int qh = (n0 - 2048 + wc*64) >> 6;
      int bidx = m0 >> 11;
      size_t hb = ((size_t)bidx*NH + qh)*(size_t)NT;
      float invf[2];
      invf[0] = __expf(-(float)l15 * 0.2878231366242557f);         // i = l15
      invf[1] = __expf(-(float)(16 + l15) * 0.2878231366242557f);  // i = 16+l15
      #pragma unroll
      for (int mi=0;mi<4;mi++){
        #pragma unroll
        for (int r2=0;r2<4;r2++){
          int tp = (m0 & 2047) + wr*64 + mi*16 + lg*4 + r2;
          #pragma unroll
          for (int bb2=0;bb2<2;bb2++){
            float x1 = acc[mi][bb2][r2];
            float x2 = acc[mi][bb2+2][r2];
            float fr = (float)tp * invf[bb2];
            float sn, cs;
            sincosf(fr, &sn, &cs);
            float o0 = (x1*cs - x2*sn)*mult;
            float o1 = (x1*sn + x2*cs)*mult;
            int i2 = (bb2<<4) + l15;
            *(unsigned*)&C[(hb + tp)*192 + 128 + 2*i2] = cvtpk(o0, o1);
          }
        }
      }
      return;
    }
  }
  #pragma unroll
  for (int mi=0;mi<4;mi++){
    #pragma unroll
    for (int nj=0;nj<4;nj++){
      f32x4 v = acc[mi][nj];
      int gr0 = m0 + wr*64 + mi*16 + lg*4;
      int gc  = n0 + wc*64 + nj*16 + l15;
      if constexpr (MODE==0){
        if (gc < N){
          #pragma unroll
          for (int r2=0;r2<4;r2++) C[(size_t)(gr0+r2)*N + gc] = __float2bfloat16(v[r2]*mult);
        }
      } else if constexpr (MODE==2){
        float bb = bias[gc];
        #pragma unroll
        for (int r2=0;r2<4;r2++) Cf[(size_t)(gr0+r2)*N + gc] = v[r2]*mult + bb;
      } else if constexpr (MODE==4){
        int bidx = m0 >> 11;
        int tl0 = (m0 & 2047) + wr*64 + mi*16 + lg*4;
        if (gc < 2048){
          int hq = gc >> 7, dl = gc & 127;
          size_t base = ((size_t)bidx*NH + hq)*(size_t)NT;
          #pragma unroll
          for (int r2=0;r2<4;r2++) C[(base + tl0 + r2)*192 + dl] = __float2bfloat16(v[r2]);
        } else {
          int g2 = gc - 2048;
          int hq = g2 >> 7, dl = g2 & 127;
          s4_t pk;
          #pragma unroll
          for (int r2=0;r2<4;r2++){
            union { bf16 b; unsigned short u; } cvu;
            cvu.b = __float2bfloat16(v[r2]);
            pk[r2] = (short)cvu.u;
          }
          *(s4_t*)&C2[(((size_t)bidx*NH + hq)*NHD + dl)*NT + tl0] = pk;
        }
      } else { // MODE 5, Q half (n0 < 2048)
        int bidx = m0 >> 11;
        int tl0 = (m0 & 2047) + wr*64 + mi*16 + lg*4;
        int hq = gc >> 7, dl = gc & 127;
        size_t base = ((size_t)bidx*NH + hq)*(size_t)NT;
        #pragma unroll
        for (int r2=0;r2<4;r2++) C[(base + tl0 + r2)*192 + dl] = __float2bfloat16(v[r2]*mult);
      }
    }
  }
}

// ---------------- K-RoPE (krp in combined buffer, row stride 1088) ----------------
__global__ __launch_bounds__(128) void rope_k(const bf16* __restrict__ krp,
    bf16* __restrict__ Kf)
{
  int bt = blockIdx.x*2 + (threadIdx.x>>6);
  int d = threadIdx.x & 63;
  int b = bt >> 11, tpos = bt & 2047;
  int i = d >> 1;
  float inv = __expf(-(float)i * 0.2878231366242557f);
  float fr = (float)tpos * inv;
  float sn, cs;
  sincosf(fr, &sn, &cs);

  float x1 = __bfloat162float(krp[(size_t)bt*1088 + i]);
  float x2 = __bfloat162float(krp[(size_t)bt*1088 + 32 + i]);
  float kv = (d&1) ? (x1*sn + x2*cs) : (x1*cs - x2*sn);
  bf16 kvb = __float2bfloat16(kv);
  size_t base = ((size_t)b*NH*NT + tpos)*192;
  #pragma unroll
  for (int h=0;h<NH;h++) Kf[base + (size_t)h*NT*192 + 128 + d] = kvb;
}

// ---------------- Flash attention (swapped-operand, 32x32x16) ----------------
// 8-wave block, QBLK=256, DMA staging (pre-swizzled source), K/V double-buffered.
// Q pre-scaled by (1/sqrt(192))*log2(e): softmax uses __builtin_amdgcn_exp2f
// (single v_exp_f32, which is base-2 natively). Defer-max threshold 8*log2e.
static __device__ inline void plswap(unsigned &a, unsigned &b){
  uint2v r = __builtin_amdgcn_permlane32_swap(a, b, false, false);
  a = r[0]; b = r[1];
}

__global__ __launch_bounds__(512,2) void attn_kernel(const bf16* __restrict__ Qf,
    const bf16* __restrict__ Kf, const bf16* __restrict__ Vt, bf16* __restrict__ ctx)
{
  __shared__ __align__(16) bf16 smem[40960];   // 81920 B: 2 x (12288 K + 8192 V) elems

  const int lin = blockIdx.x;
  const int swz = (lin & 7)*32 + (lin >> 3);      // 256 = 8*32 -> bijective
  const int qt = swz & 7, bh = swz >> 3;
  const int b = bh >> 4, h = bh & 15;
  const int q0 = qt * 256;
  const int t = threadIdx.x, lane = t&63, w = t>>6;   // w in 0..7
  const int l31 = lane&31, hi = lane>>5;
  const int rsw = (l31&7)<<4;
  const int hib = hi*16;
  const int wbase = t & 448;                       // wave-uniform thread base

  const bf16* Qp  = Qf + ((size_t)bh*NT + q0)*192;
  const bf16* Kp  = Kf + (size_t)bh*NT*192;
  const bf16* Vtp = Vt + (size_t)bh*NHD*NT;

  short8 qf[12];
  #pragma unroll
  for (int kk=0;kk<12;kk++)
    qf[kk] = *(const short8*)(Qp + (size_t)(w*32 + l31)*192 + kk*16 + hi*8);

  f32x16 o[4];
  #pragma unroll
  for (int Dt=0;Dt<4;Dt++)
    #pragma unroll
    for (int r=0;r<16;r++) o[Dt][r] = 0.f;
  float mrun = -1e30f, lrun = 0.f;

  // DMA-stage tile kt into buf: K 64x192 + V^T 128x64 (elems), pre-swizzled source
  auto stage = [&](int kt, bf16* buf){
    const bf16* Ksrc = Kp + (size_t)kt*64*192;
    #pragma unroll
    for (int j=0;j<3;j++){
      int c = j*512 + t;                     // 1536 chunks of 8 elems
      int r = c/24, ce = (c%24)*8;           // row, col-elem (linear dest)
      gl_lds16(Ksrc + (size_t)r*192 + (ce ^ ((r&7)<<3)), buf + (size_t)(j*512 + wbase)*8);
    }
    bf16* vb = buf + 12288;
    #pragma unroll
    for (int j=0;j<2;j++){
      int c = j*512 + t;                     // 1024 chunks
      int r = c>>3, ce = (c&7)*8;
      gl_lds16(Vtp + (size_t)r*NT + kt*64 + (ce ^ ((r&7)<<3)), vb + (size_t)(j*512 + wbase)*8);
    }
  };

  stage(0, smem);
  __syncthreads();   // drains vmcnt -> tile 0 resident

  for (int kt=0; kt<NT/64; kt++){
    const char* KsB  = (const char*)(smem + (kt&1)*20480);
    const char* VTsB = KsB + 24576;
    if (kt+1 < NT/64) stage(kt+1, smem + ((kt+1)&1)*20480);  // DMA overlaps compute

    // S^T[key][q]: A = K rows (key = Mt*32 + l31), B = Q  (S in log2e units)
    f32x16 sa[2];
    #pragma unroll
    for (int Mt=0;Mt<2;Mt++)
      #pragma unroll
      for (int r=0;r<16;r++) sa[Mt][r] = 0.f;
    __builtin_amdgcn_s_setprio(1);
    #pragma unroll
    for (int kk=0;kk<12;kk++){
      int cb = kk*32 + hib;
      short8 kf0 = *(const short8*)(KsB + (size_t)l31*384        + ((cb) ^ rsw));
      short8 kf1 = *(const short8*)(KsB + (size_t)(l31+32)*384   + ((cb) ^ rsw));
      sa[0] = __builtin_amdgcn_mfma_f32_32x32x16_bf16(kf0, qf[kk], sa[0], 0,0,0);
      sa[1] = __builtin_amdgcn_mfma_f32_32x32x16_bf16(kf1, qf[kk], sa[1], 0,0,0);
    }
    __builtin_amdgcn_s_setprio(0);

    float mx[8];
    #pragma unroll
    for (int i2=0;i2<8;i2++)
      mx[i2] = fmaxf(fmaxf(sa[0][2*i2], sa[0][2*i2+1]), fmaxf(sa[1][2*i2], sa[1][2*i2+1]));
    float tm = fmaxf(fmaxf(fmaxf(mx[0],mx[1]),fmaxf(mx[2],mx[3])),
                     fmaxf(fmaxf(mx[4],mx[5]),fmaxf(mx[6],mx[7])));
    tm = fmaxf(tm, __shfl_xor(tm, 32));

    if (__any(tm > mrun + 11.5416f)){   // 8 * log2(e)
      float mn = fmaxf(mrun, tm);
      float alpha = __builtin_amdgcn_exp2f(mrun - mn);
      mrun = mn;
      lrun *= alpha;
      #pragma unroll
      for (int Dt=0;Dt<4;Dt++)
        #pragma unroll
        for (int r=0;r<16;r++) o[Dt][r] *= alpha;
    }

    #pragma unroll
    for (int Mt=0;Mt<2;Mt++)
      #pragma unroll
      for (int r=0;r<16;r++) sa[Mt][r] = __builtin_amdgcn_exp2f(sa[Mt][r] - mrun);
    float sm[8];
    #pragma unroll
    for (int i2=0;i2<8;i2++)
      sm[i2] = (sa[0][2*i2] + sa[0][2*i2+1]) + (sa[1][2*i2] + sa[1][2*i2+1]);
    float rs = ((sm[0]+sm[1])+(sm[2]+sm[3])) + ((sm[4]+sm[5])+(sm[6]+sm[7]));
    rs += __shfl_xor(rs, 32);
    lrun += rs;

    short8 pf[4];
    #pragma unroll
    for (int Mt=0;Mt<2;Mt++){
      unsigned u[8];
      #pragma unroll
      for (int p8=0;p8<8;p8++) u[p8] = cvtpk(sa[Mt][2*p8], sa[Mt][2*p8+1]);
      plswap(u[0], u[2]); plswap(u[1], u[3]);
      plswap(u[4], u[6]); plswap(u[5], u[7]);
      union { unsigned du[4]; short8 s8; } f0, f1;
      f0.du[0]=u[0]; f0.du[1]=u[1]; f0.du[2]=u[2]; f0.du[3]=u[3];
      f1.du[0]=u[4]; f1.du[1]=u[5]; f1.du[2]=u[6]; f1.du[3]=u[7];
      pf[2*Mt+0] = f0.s8;
      pf[2*Mt+1] = f1.s8;
    }

    // O^T += V^T @ P^T
    __builtin_amdgcn_s_setprio(1);
    #pragma unroll
    for (int kw=0;kw<4;kw++){
      int cb = kw*32 + hib;
      #pragma unroll
      for (int Dt=0;Dt<4;Dt++){
        short8 vf = *(const short8*)(VTsB + (size_t)(Dt*32 + l31)*128 + ((cb) ^ rsw));
        o[Dt] = __builtin_amdgcn_mfma_f32_32x32x16_bf16(vf, pf[kw], o[Dt], 0,0,0);
      }
    }
    __builtin_amdgcn_s_setprio(0);
    __syncthreads();   // drains DMA for tile kt+1; protects buf reuse
  }

  float il = 1.0f / lrun;
  bf16* Es = smem;    // 256 rows x 140 elems = 71680 B < 81920 B
  const int EROW = 140;
  const int ebase = w*32*EROW;
  #pragma unroll
  for (int Dt=0;Dt<4;Dt++)
    #pragma unroll
    for (int r=0;r<16;r+=2){
      int d = Dt*32 + (r&3) + 8*(r>>2) + 4*hi;
      *(unsigned*)&Es[ebase + l31*EROW + d] = cvtpk(o[Dt][r]*il, o[Dt][r+1]*il);
    }
  __syncthreads();
  int q = lane>>1, halfd = lane&1;
  size_t gq = q0 + w*32 + q;
  size_t obase = (((size_t)b*NT + gq)*NH + h)*NHD + halfd*64;
  const int eb2 = ebase + q*EROW + halfd*64;
  #pragma unroll
  for (int pp=0;pp<8;pp++){
    union { s4_t h[2]; short8 s; } uu;
    uu.h[0] = *(const s4_t*)&Es[eb2 + pp*8];
    uu.h[1] = *(const s4_t*)&Es[eb2 + pp*8 + 4];
    *(short8*)&ctx[obase + pp*8] = uu.s;
  }
}

// ---------------- host ----------------
extern "C" void kernel_launch(void* const* d_in, const int* in_sizes, int n_in,
                              void* d_out, int out_size, void* d_ws, size_t ws_size,
                              hipStream_t stream)
{
  const float* x     = (const float*)d_in[0];
  const float* W_DKV = (const float*)d_in[1];
  const float* W_DQ  = (const float*)d_in[2];
  const float* W_UK  = (const float*)d_in[3];
  const float* W_UV  = (const float*)d_in[4];
  const float* W_UQ  = (const float*)d_in[5];
  const float* W_KR  = (const float*)d_in[6];
  const float* W_QR  = (const float*)d_in[7];
  const float* W_O   = (const float*)d_in[8];
  const float* b_O   = (const float*)d_in[9];

  // (1/sqrt(192)) * log2(e): QK^T lands in log2e units -> softmax uses raw exp2
  const float scale = 0.07216878364870323f * 1.4426950408889634f;

  char* ws = (char*)d_ws;
  bf16* xb    = (bf16*)(ws + 0);           // [4096][2048]
  bf16* wcomb = (bf16*)(ws + 16777216);    // [1088][2048]  (W_DKV^T ; W_DQ^T ; W_KR^T)
  bf16* wuk   = (bf16*)(ws + 21233664);    // [2048][512]   (contiguous with wuv)
  bf16* wuv   = (bf16*)(ws + 23330816);
  bf16* wuq   = (bf16*)(ws + 25427968);    // (contiguous with wqr)
  bf16* wqr   = (bf16*)(ws + 27525120);    // [1024][512]
  bf16* wo    = (bf16*)(ws + 28573696);    // [2048][2048]
  bf16* comb  = (bf16*)(ws + 36962304);    // [4096][1088]  (ckv | cq | krp)
  bf16* Qf    = (bf16*)(ws + 54263808);    // [2,16,2048,192]
  bf16* Kf    = (bf16*)(ws + 79429632);    // [2,16,2048,192]
  bf16* vt    = (bf16*)(ws + 104595456);   // [2,16,128,2048]  (V transposed)
  bf16* ctxb  = (bf16*)(ws + 121372672);   // [4096][2048]

  bf16* ckv = comb;          // cols 0-511,   lda 1088
  bf16* cq  = comb + 512;    // cols 512-1023
  bf16* krp = comb + 1024;   // cols 1024-1087

  cvt_kernel<<<8192,256,0,stream>>>(x, xb);

  TAll ta;
  ta.src[0]=W_DKV; ta.dst[0]=wcomb;             ta.K[0]=2048; ta.N[0]=512;
  ta.src[1]=W_DQ;  ta.dst[1]=wcomb + 512*2048;  ta.K[1]=2048; ta.N[1]=512;
  ta.src[2]=W_KR;  ta.dst[2]=wcomb + 1024*2048; ta.K[2]=2048; ta.N[2]=64;
  ta.src[3]=W_UK;  ta.dst[3]=wuk;               ta.K[3]=512;  ta.N[3]=2048;
  ta.src[4]=W_UV;  ta.dst[4]=wuv;               ta.K[4]=512;  ta.N[4]=2048;
  ta.src[5]=W_UQ;  ta.dst[5]=wuq;               ta.K[5]=512;  ta.N[5]=2048;
  ta.src[6]=W_QR;  ta.dst[6]=wqr;               ta.K[6]=512;  ta.N[6]=1024;
  ta.src[7]=W_O;   ta.dst[7]=wo;                ta.K[7]=2048; ta.N[7]=2048;
  ta.cum[0]=0;
  for (int i=0;i<8;i++) ta.cum[i+1] = ta.cum[i] + (ta.N[i]/32)*(ta.K[i]/32);
  tconv_all<<<ta.cum[8],256,0,stream>>>(ta);

  // merged x-projection: [4096,2048] @ [1088,2048]^T -> comb
  gemm_bt<0><<<dim3(32,9), 256,0,stream>>>(xb, wcomb, comb, nullptr, nullptr, nullptr, 4096, 1088, 2048, 2048, 1.0f);

  // K-RoPE (krp ready after x-proj)
  rope_k<<<2048,128,0,stream>>>(krp, Kf);

  // merged KV up-projection: ckv @ [wuk;wuv]^T  (N=4096)
  gemm_bt<4><<<dim3(32,32),256,0,stream>>>(ckv, wuk, Kf, vt, nullptr, nullptr, 4096, 4096, 512, 1088, 1.0f);
  // merged Q/QR up-projection with fused Q-RoPE: cq @ [wuq;wqr]^T  (N=3072)
  gemm_bt<5><<<dim3(32,24),256,0,stream>>>(cq, wuq, Qf, nullptr, nullptr, nullptr, 4096, 3072, 512, 1088, scale);

  attn_kernel<<<256,512,0,stream>>>(Qf, Kf, vt, ctxb);
  gemm_bt<2><<<dim3(32,16),256,0,stream>>>(ctxb, wo, nullptr, nullptr, (float*)d_out, b_O, 4096, 2048, 2048, 2048, 1.0f);
}

// Round 25
// 258.174 us; speedup vs baseline: 1.0644x; 1.0236x over previous
//
#include <hip/hip_runtime.h>
#include <hip/hip_bf16.h>

typedef __attribute__((ext_vector_type(8))) short short8;
typedef __attribute__((ext_vector_type(4))) short s4_t;
typedef __attribute__((ext_vector_type(4))) float f32x4;
typedef __attribute__((ext_vector_type(16))) float f32x16;
typedef __attribute__((ext_vector_type(2))) unsigned uint2v;
typedef __hip_bfloat16 bf16;

#define NB 2
#define NT 2048
#define NDIM 2048
#define NH 16
#define NHD 128
#define NDC 512
#define NDR 64

// async global->LDS, 16B per lane; lds base must be wave-uniform (HW: base + lane*16)
__device__ __forceinline__ void gl_lds16(const bf16* g, bf16* l){
  __builtin_amdgcn_global_load_lds(
      (const __attribute__((address_space(1))) void*)(const void*)g,
      (__attribute__((address_space(3))) void*)(void*)l, 16, 0, 0);
}

static __device__ inline unsigned cvtpk(float lo, float hi){
  unsigned u;
  asm("v_cvt_pk_bf16_f32 %0, %1, %2" : "=v"(u) : "v"(lo), "v"(hi));
  return u;
}

// ---------------- f32 -> bf16 convert (x) ----------------
__global__ __launch_bounds__(256) void cvt_kernel(const float* __restrict__ src, bf16* __restrict__ dst){
  int i = (blockIdx.x*256 + threadIdx.x)*4;
  float4 v = *(const float4*)(src + i);
  dst[i+0] = __float2bfloat16(v.x);
  dst[i+1] = __float2bfloat16(v.y);
  dst[i+2] = __float2bfloat16(v.z);
  dst[i+3] = __float2bfloat16(v.w);
}

// ---------------- batched transpose+convert: 8 weights in one launch ----------------
struct TAll {
  const float* src[8];
  bf16* dst[8];
  int K[8];
  int N[8];
  int cum[9];
};
__global__ __launch_bounds__(256) void tconv_all(TAll a){
  __shared__ float tile[32][33];
  int bid = blockIdx.x;
  int i = 0;
  #pragma unroll
  for (int j=0;j<8;j++) if (bid >= a.cum[j+1]) i = j+1;
  const float* W = a.src[i];
  bf16* Wt = a.dst[i];
  int K = a.K[i], N = a.N[i];
  int tl = bid - a.cum[i];
  int ntx = N >> 5;
  int n0 = (tl % ntx)*32, k0 = (tl / ntx)*32;
  int tx = threadIdx.x & 31, ty = threadIdx.x >> 5;
  #pragma unroll
  for (int j=0;j<32;j+=8) tile[ty+j][tx] = W[(size_t)(k0+ty+j)*N + n0 + tx];
  __syncthreads();
  #pragma unroll
  for (int j=0;j<32;j+=8) Wt[(size_t)(n0+ty+j)*K + k0 + tx] = __float2bfloat16(tile[tx][ty+j]);
}

// ---------------- GEMM: C[M,N] = A[M,K] @ Bt[N,K]^T  (bf16 in, f32 acc) ----------------
// m97 structure: global_load_lds width-16 staging into linear LDS, 2 barriers/K-step.
// Occupancy 4 blocks/CU (128 KB LDS): extra TLP covers the barrier vmcnt-drain.
// MODE 0: C bf16 row-major [M,N] (guarded on N)
// MODE 2: Cf f32 row-major [M,N] + bias
// MODE 4: KV merged: gc<2048 -> Kf heads layout (C); else -> V^T layout [bh][d][t] (C2)
// MODE 5: QQR merged: gc<2048 -> Qf heads layout *mult (C); else -> fused Q-RoPE into
//         Qf[...,128+2i] (rotation pair (i,i+32) lives in nj and nj^2 of same thread)
template<int MODE>
__global__ __launch_bounds__(256,4) void gemm_bt(const bf16* __restrict__ A,
    const bf16* __restrict__ Bt, bf16* __restrict__ C, bf16* __restrict__ C2,
    float* __restrict__ Cf, const float* __restrict__ bias,
    int M, int N, int K, int lda, float mult)
{
  __shared__ bf16 As[128*64];
  __shared__ bf16 Bs[128*64];
  const int m0 = blockIdx.x*128, n0 = blockIdx.y*128;
  const int t = threadIdx.x, lane = t&63, w = t>>6;
  const int wr = w>>1, wc = w&1;
  const int l15 = lane&15, lg = lane>>4;
  const int wbase = t & 192;   // w*64

  f32x4 acc[4][4];
  #pragma unroll
  for (int mi=0;mi<4;mi++)
    #pragma unroll
    for (int nj=0;nj<4;nj++) acc[mi][nj] = (f32x4){0.f,0.f,0.f,0.f};

  for (int k0=0;k0<K;k0+=64){
    __syncthreads();
    #pragma unroll
    for (int j=0;j<4;j++){
      int c = j*256 + t;
      int r = c>>3, cc = (c&7)*8;
      gl_lds16(A + (size_t)(m0+r)*lda + k0 + cc, As + (size_t)(j*256 + wbase)*8);
      int bn = n0 + r; if (bn > N-1) bn = N-1;
      gl_lds16(Bt + (size_t)bn*K + k0 + cc, Bs + (size_t)(j*256 + wbase)*8);
    }
    __syncthreads();
    #pragma unroll
    for (int kk=0;kk<2;kk++){
      short8 af[4], bfv[4];
      #pragma unroll
      for (int mi=0;mi<4;mi++) af[mi] = *(const short8*)&As[(wr*64+mi*16+l15)*64 + kk*32+lg*8];
      #pragma unroll
      for (int nj=0;nj<4;nj++) bfv[nj] = *(const short8*)&Bs[(wc*64+nj*16+l15)*64 + kk*32+lg*8];
      #pragma unroll
      for (int mi=0;mi<4;mi++)
        #pragma unroll
        for (int nj=0;nj<4;nj++)
          acc[mi][nj] = __builtin_amdgcn_mfma_f32_16x16x32_bf16(af[mi], bfv[nj], acc[mi][nj], 0,0,0);
    }
  }

  // epilogue: D layout col=lane&15, row=(lane>>4)*4+reg  [verified m89]
  if constexpr (MODE==5){
    if (n0 >= 2048){
      // fused Q-RoPE: this block's cols are entirely q_R (boundary 2048 is block-aligned)
      int qh = (n0 - 2048 + wc*64) >> 6;
      int bidx = m0 >> 11;
      size_t hb = ((size_t)bidx*NH + qh)*(size_t)NT;
      float invf[2];
      invf[0] = __expf(-(float)l15 * 0.2878231366242557f);         // i = l15
      invf[1] = __expf(-(float)(16 + l15) * 0.2878231366242557f);  // i = 16+l15
      #pragma unroll
      for (int mi=0;mi<4;mi++){
        #pragma unroll
        for (int r2=0;r2<4;r2++){
          int tp = (m0 & 2047) + wr*64 + mi*16 + lg*4 + r2;
          #pragma unroll
          for (int bb2=0;bb2<2;bb2++){
            float x1 = acc[mi][bb2][r2];
            float x2 = acc[mi][bb2+2][r2];
            float fr = (float)tp * invf[bb2];
            float sn, cs;
            sincosf(fr, &sn, &cs);
            float o0 = (x1*cs - x2*sn)*mult;
            float o1 = (x1*sn + x2*cs)*mult;
            int i2 = (bb2<<4) + l15;
            *(unsigned*)&C[(hb + tp)*192 + 128 + 2*i2] = cvtpk(o0, o1);
          }
        }
      }
      return;
    }
  }
  #pragma unroll
  for (int mi=0;mi<4;mi++){
    #pragma unroll
    for (int nj=0;nj<4;nj++){
      f32x4 v = acc[mi][nj];
      int gr0 = m0 + wr*64 + mi*16 + lg*4;
      int gc  = n0 + wc*64 + nj*16 + l15;
      if constexpr (MODE==0){
        if (gc < N){
          #pragma unroll
          for (int r2=0;r2<4;r2++) C[(size_t)(gr0+r2)*N + gc] = __float2bfloat16(v[r2]*mult);
        }
      } else if constexpr (MODE==2){
        float bb = bias[gc];
        #pragma unroll
        for (int r2=0;r2<4;r2++) Cf[(size_t)(gr0+r2)*N + gc] = v[r2]*mult + bb;
      } else if constexpr (MODE==4){
        int bidx = m0 >> 11;
        int tl0 = (m0 & 2047) + wr*64 + mi*16 + lg*4;
        if (gc < 2048){
          int hq = gc >> 7, dl = gc & 127;
          size_t base = ((size_t)bidx*NH + hq)*(size_t)NT;
          #pragma unroll
          for (int r2=0;r2<4;r2++) C[(base + tl0 + r2)*192 + dl] = __float2bfloat16(v[r2]);
        } else {
          int g2 = gc - 2048;
          int hq = g2 >> 7, dl = g2 & 127;
          s4_t pk;
          #pragma unroll
          for (int r2=0;r2<4;r2++){
            union { bf16 b; unsigned short u; } cvu;
            cvu.b = __float2bfloat16(v[r2]);
            pk[r2] = (short)cvu.u;
          }
          *(s4_t*)&C2[(((size_t)bidx*NH + hq)*NHD + dl)*NT + tl0] = pk;
        }
      } else { // MODE 5, Q half (n0 < 2048)
        int bidx = m0 >> 11;
        int tl0 = (m0 & 2047) + wr*64 + mi*16 + lg*4;
        int hq = gc >> 7, dl = gc & 127;
        size_t base = ((size_t)bidx*NH + hq)*(size_t)NT;
        #pragma unroll
        for (int r2=0;r2<4;r2++) C[(base + tl0 + r2)*192 + dl] = __float2bfloat16(v[r2]*mult);
      }
    }
  }
}

// ---------------- K-RoPE (krp in combined buffer, row stride 1088) ----------------
__global__ __launch_bounds__(128) void rope_k(const bf16* __restrict__ krp,
    bf16* __restrict__ Kf)
{
  int bt = blockIdx.x*2 + (threadIdx.x>>6);
  int d = threadIdx.x & 63;
  int b = bt >> 11, tpos = bt & 2047;
  int i = d >> 1;
  float inv = __expf(-(float)i * 0.2878231366242557f);
  float fr = (float)tpos * inv;
  float sn, cs;
  sincosf(fr, &sn, &cs);

  float x1 = __bfloat162float(krp[(size_t)bt*1088 + i]);
  float x2 = __bfloat162float(krp[(size_t)bt*1088 + 32 + i]);
  float kv = (d&1) ? (x1*sn + x2*cs) : (x1*cs - x2*sn);
  bf16 kvb = __float2bfloat16(kv);
  size_t base = ((size_t)b*NH*NT + tpos)*192;
  #pragma unroll
  for (int h=0;h<NH;h++) Kf[base + (size_t)h*NT*192 + 128 + d] = kvb;
}

// ---------------- Flash attention (swapped-operand, 32x32x16) ----------------
// 8-wave block, QBLK=256, DMA staging (pre-swizzled source), K/V double-buffered.
// Q pre-scaled by (1/sqrt(192))*log2(e): softmax uses __builtin_amdgcn_exp2f
// (single v_exp_f32, which is base-2 natively). Defer-max threshold 8*log2e.
static __device__ inline void plswap(unsigned &a, unsigned &b){
  uint2v r = __builtin_amdgcn_permlane32_swap(a, b, false, false);
  a = r[0]; b = r[1];
}

__global__ __launch_bounds__(512,2) void attn_kernel(const bf16* __restrict__ Qf,
    const bf16* __restrict__ Kf, const bf16* __restrict__ Vt, bf16* __restrict__ ctx)
{
  __shared__ __align__(16) bf16 smem[40960];   // 81920 B: 2 x (12288 K + 8192 V) elems

  const int lin = blockIdx.x;
  const int swz = (lin & 7)*32 + (lin >> 3);      // 256 = 8*32 -> bijective
  const int qt = swz & 7, bh = swz >> 3;
  const int b = bh >> 4, h = bh & 15;
  const int q0 = qt * 256;
  const int t = threadIdx.x, lane = t&63, w = t>>6;   // w in 0..7
  const int l31 = lane&31, hi = lane>>5;
  const int rsw = (l31&7)<<4;
  const int hib = hi*16;
  const int wbase = t & 448;                       // wave-uniform thread base

  const bf16* Qp  = Qf + ((size_t)bh*NT + q0)*192;
  const bf16* Kp  = Kf + (size_t)bh*NT*192;
  const bf16* Vtp = Vt + (size_t)bh*NHD*NT;

  short8 qf[12];
  #pragma unroll
  for (int kk=0;kk<12;kk++)
    qf[kk] = *(const short8*)(Qp + (size_t)(w*32 + l31)*192 + kk*16 + hi*8);

  f32x16 o[4];
  #pragma unroll
  for (int Dt=0;Dt<4;Dt++)
    #pragma unroll
    for (int r=0;r<16;r++) o[Dt][r] = 0.f;
  float mrun = -1e30f, lrun = 0.f;

  // DMA-stage tile kt into buf: K 64x192 + V^T 128x64 (elems), pre-swizzled source
  auto stage = [&](int kt, bf16* buf){
    const bf16* Ksrc = Kp + (size_t)kt*64*192;
    #pragma unroll
    for (int j=0;j<3;j++){
      int c = j*512 + t;                     // 1536 chunks of 8 elems
      int r = c/24, ce = (c%24)*8;           // row, col-elem (linear dest)
      gl_lds16(Ksrc + (size_t)r*192 + (ce ^ ((r&7)<<3)), buf + (size_t)(j*512 + wbase)*8);
    }
    bf16* vb = buf + 12288;
    #pragma unroll
    for (int j=0;j<2;j++){
      int c = j*512 + t;                     // 1024 chunks
      int r = c>>3, ce = (c&7)*8;
      gl_lds16(Vtp + (size_t)r*NT + kt*64 + (ce ^ ((r&7)<<3)), vb + (size_t)(j*512 + wbase)*8);
    }
  };

  stage(0, smem);
  __syncthreads();   // drains vmcnt -> tile 0 resident

  for (int kt=0; kt<NT/64; kt++){
    const char* KsB  = (const char*)(smem + (kt&1)*20480);
    const char* VTsB = KsB + 24576;
    if (kt+1 < NT/64) stage(kt+1, smem + ((kt+1)&1)*20480);  // DMA overlaps compute

    // S^T[key][q]: A = K rows (key = Mt*32 + l31), B = Q  (S in log2e units)
    f32x16 sa[2];
    #pragma unroll
    for (int Mt=0;Mt<2;Mt++)
      #pragma unroll
      for (int r=0;r<16;r++) sa[Mt][r] = 0.f;
    __builtin_amdgcn_s_setprio(1);
    #pragma unroll
    for (int kk=0;kk<12;kk++){
      int cb = kk*32 + hib;
      short8 kf0 = *(const short8*)(KsB + (size_t)l31*384        + ((cb) ^ rsw));
      short8 kf1 = *(const short8*)(KsB + (size_t)(l31+32)*384   + ((cb) ^ rsw));
      sa[0] = __builtin_amdgcn_mfma_f32_32x32x16_bf16(kf0, qf[kk], sa[0], 0,0,0);
      sa[1] = __builtin_amdgcn_mfma_f32_32x32x16_bf16(kf1, qf[kk], sa[1], 0,0,0);
    }
    __builtin_amdgcn_s_setprio(0);

    float mx[8];
    #pragma unroll
    for (int i2=0;i2<8;i2++)
      mx[i2] = fmaxf(fmaxf(sa[0][2*i2], sa[0][2*i2+1]), fmaxf(sa[1][2*i2], sa[1][2*i2+1]));
    float tm = fmaxf(fmaxf(fmaxf(mx[0],mx[1]),fmaxf(mx[2],mx[3])),
                     fmaxf(fmaxf(mx[4],mx[5]),fmaxf(mx[6],mx[7])));
    tm = fmaxf(tm, __shfl_xor(tm, 32));

    if (__any(tm > mrun + 11.5416f)){   // 8 * log2(e)
      float mn = fmaxf(mrun, tm);
      float alpha = __builtin_amdgcn_exp2f(mrun - mn);
      mrun = mn;
      lrun *= alpha;
      #pragma unroll
      for (int Dt=0;Dt<4;Dt++)
        #pragma unroll
        for (int r=0;r<16;r++) o[Dt][r] *= alpha;
    }

    #pragma unroll
    for (int Mt=0;Mt<2;Mt++)
      #pragma unroll
      for (int r=0;r<16;r++) sa[Mt][r] = __builtin_amdgcn_exp2f(sa[Mt][r] - mrun);
    float sm[8];
    #pragma unroll
    for (int i2=0;i2<8;i2++)
      sm[i2] = (sa[0][2*i2] + sa[0][2*i2+1]) + (sa[1][2*i2] + sa[1][2*i2+1]);
    float rs = ((sm[0]+sm[1])+(sm[2]+sm[3])) + ((sm[4]+sm[5])+(sm[6]+sm[7]));
    rs += __shfl_xor(rs, 32);
    lrun += rs;

    short8 pf[4];
    #pragma unroll
    for (int Mt=0;Mt<2;Mt++){
      unsigned u[8];
      #pragma unroll
      for (int p8=0;p8<8;p8++) u[p8] = cvtpk(sa[Mt][2*p8], sa[Mt][2*p8+1]);
      plswap(u[0], u[2]); plswap(u[1], u[3]);
      plswap(u[4], u[6]); plswap(u[5], u[7]);
      union { unsigned du[4]; short8 s8; } f0, f1;
      f0.du[0]=u[0]; f0.du[1]=u[1]; f0.du[2]=u[2]; f0.du[3]=u[3];
      f1.du[0]=u[4]; f1.du[1]=u[5]; f1.du[2]=u[6]; f1.du[3]=u[7];
      pf[2*Mt+0] = f0.s8;
      pf[2*Mt+1] = f1.s8;
    }

    // O^T += V^T @ P^T
    __builtin_amdgcn_s_setprio(1);
    #pragma unroll
    for (int kw=0;kw<4;kw++){
      int cb = kw*32 + hib;
      #pragma unroll
      for (int Dt=0;Dt<4;Dt++){
        short8 vf = *(const short8*)(VTsB + (size_t)(Dt*32 + l31)*128 + ((cb) ^ rsw));
        o[Dt] = __builtin_amdgcn_mfma_f32_32x32x16_bf16(vf, pf[kw], o[Dt], 0,0,0);
      }
    }
    __builtin_amdgcn_s_setprio(0);
    __syncthreads();   // drains DMA for tile kt+1; protects buf reuse
  }

  float il = 1.0f / lrun;
  bf16* Es = smem;    // 256 rows x 140 elems = 71680 B < 81920 B
  const int EROW = 140;
  const int ebase = w*32*EROW;
  #pragma unroll
  for (int Dt=0;Dt<4;Dt++)
    #pragma unroll
    for (int r=0;r<16;r+=2){
      int d = Dt*32 + (r&3) + 8*(r>>2) + 4*hi;
      *(unsigned*)&Es[ebase + l31*EROW + d] = cvtpk(o[Dt][r]*il, o[Dt][r+1]*il);
    }
  __syncthreads();
  int q = lane>>1, halfd = lane&1;
  size_t gq = q0 + w*32 + q;
  size_t obase = (((size_t)b*NT + gq)*NH + h)*NHD + halfd*64;
  const int eb2 = ebase + q*EROW + halfd*64;
  #pragma unroll
  for (int pp=0;pp<8;pp++){
    union { s4_t h[2]; short8 s; } uu;
    uu.h[0] = *(const s4_t*)&Es[eb2 + pp*8];
    uu.h[1] = *(const s4_t*)&Es[eb2 + pp*8 + 4];
    *(short8*)&ctx[obase + pp*8] = uu.s;
  }
}

// ---------------- host ----------------
extern "C" void kernel_launch(void* const* d_in, const int* in_sizes, int n_in,
                              void* d_out, int out_size, void* d_ws, size_t ws_size,
                              hipStream_t stream)
{
  const float* x     = (const float*)d_in[0];
  const float* W_DKV = (const float*)d_in[1];
  const float* W_DQ  = (const float*)d_in[2];
  const float* W_UK  = (const float*)d_in[3];
  const float* W_UV  = (const float*)d_in[4];
  const float* W_UQ  = (const float*)d_in[5];
  const float* W_KR  = (const float*)d_in[6];
  const float* W_QR  = (const float*)d_in[7];
  const float* W_O   = (const float*)d_in[8];
  const float* b_O   = (const float*)d_in[9];

  // (1/sqrt(192)) * log2(e): QK^T lands in log2e units -> softmax uses raw exp2
  const float scale = 0.07216878364870323f * 1.4426950408889634f;

  char* ws = (char*)d_ws;
  bf16* xb    = (bf16*)(ws + 0);           // [4096][2048]
  bf16* wcomb = (bf16*)(ws + 16777216);    // [1088][2048]  (W_DKV^T ; W_DQ^T ; W_KR^T)
  bf16* wuk   = (bf16*)(ws + 21233664);    // [2048][512]   (contiguous with wuv)
  bf16* wuv   = (bf16*)(ws + 23330816);
  bf16* wuq   = (bf16*)(ws + 25427968);    // (contiguous with wqr)
  bf16* wqr   = (bf16*)(ws + 27525120);    // [1024][512]
  bf16* wo    = (bf16*)(ws + 28573696);    // [2048][2048]
  bf16* comb  = (bf16*)(ws + 36962304);    // [4096][1088]  (ckv | cq | krp)
  bf16* Qf    = (bf16*)(ws + 54263808);    // [2,16,2048,192]
  bf16* Kf    = (bf16*)(ws + 79429632);    // [2,16,2048,192]
  bf16* vt    = (bf16*)(ws + 104595456);   // [2,16,128,2048]  (V transposed)
  bf16* ctxb  = (bf16*)(ws + 121372672);   // [4096][2048]

  bf16* ckv = comb;          // cols 0-511,   lda 1088
  bf16* cq  = comb + 512;    // cols 512-1023
  bf16* krp = comb + 1024;   // cols 1024-1087

  cvt_kernel<<<8192,256,0,stream>>>(x, xb);

  TAll ta;
  ta.src[0]=W_DKV; ta.dst[0]=wcomb;             ta.K[0]=2048; ta.N[0]=512;
  ta.src[1]=W_DQ;  ta.dst[1]=wcomb + 512*2048;  ta.K[1]=2048; ta.N[1]=512;
  ta.src[2]=W_KR;  ta.dst[2]=wcomb + 1024*2048; ta.K[2]=2048; ta.N[2]=64;
  ta.src[3]=W_UK;  ta.dst[3]=wuk;               ta.K[3]=512;  ta.N[3]=2048;
  ta.src[4]=W_UV;  ta.dst[4]=wuv;               ta.K[4]=512;  ta.N[4]=2048;
  ta.src[5]=W_UQ;  ta.dst[5]=wuq;               ta.K[5]=512;  ta.N[5]=2048;
  ta.src[6]=W_QR;  ta.dst[6]=wqr;               ta.K[6]=512;  ta.N[6]=1024;
  ta.src[7]=W_O;   ta.dst[7]=wo;                ta.K[7]=2048; ta.N[7]=2048;
  ta.cum[0]=0;
  for (int i=0;i<8;i++) ta.cum[i+1] = ta.cum[i] + (ta.N[i]/32)*(ta.K[i]/32);
  tconv_all<<<ta.cum[8],256,0,stream>>>(ta);

  // merged x-projection: [4096,2048] @ [1088,2048]^T -> comb
  gemm_bt<0><<<dim3(32,9), 256,0,stream>>>(xb, wcomb, comb, nullptr, nullptr, nullptr, 4096, 1088, 2048, 2048, 1.0f);

  // K-RoPE (krp ready after x-proj)
  rope_k<<<2048,128,0,stream>>>(krp, Kf);

  // merged KV up-projection: ckv @ [wuk;wuv]^T  (N=4096)
  gemm_bt<4><<<dim3(32,32),256,0,stream>>>(ckv, wuk, Kf, vt, nullptr, nullptr, 4096, 4096, 512, 1088, 1.0f);
  // merged Q/QR up-projection with fused Q-RoPE: cq @ [wuq;wqr]^T  (N=3072)
  gemm_bt<5><<<dim3(32,24),256,0,stream>>>(cq, wuq, Qf, nullptr, nullptr, nullptr, 4096, 3072, 512, 1088, scale);

  attn_kernel<<<256,512,0,stream>>>(Qf, Kf, vt, ctxb);
  gemm_bt<2><<<dim3(32,16),256,0,stream>>>(ctxb, wo, nullptr, nullptr, (float*)d_out, b_O, 4096, 2048, 2048, 2048, 1.0f);
}